// Round 1
// baseline (428.607 us; speedup 1.0000x reference)
//
#include <hip/hip_runtime.h>

#define NTOK 100352   // 8*112*112
#define NPB  12544    // tokens per batch (112*112)
#define CH   256

typedef unsigned short u16;
typedef float f32x4 __attribute__((ext_vector_type(4)));
typedef short bfrag __attribute__((ext_vector_type(8)));   // 8 bf16 = 4 VGPRs

static __device__ __forceinline__ u16 f2bf(float f) {
    union { float f; unsigned u; } v; v.f = f;
    unsigned r = v.u + 0x7FFFu + ((v.u >> 16) & 1u);   // RNE
    return (u16)(r >> 16);
}
static __device__ __forceinline__ float bf2f(u16 h) {
    union { unsigned u; float f; } v; v.u = ((unsigned)h) << 16;
    return v.f;
}

// ---------------- K0: weight prep (fp32 -> bf16, fold q scale) ----------------
__global__ __launch_bounds__(256)
void swa_prep(const float* __restrict__ wq, const float* __restrict__ wk,
              const float* __restrict__ wv, const float* __restrict__ wm,
              u16* __restrict__ wcat, u16* __restrict__ wmb)
{
    int i0 = blockIdx.x * 256 + threadIdx.x;
    int stride = gridDim.x * 256;
    for (int i = i0; i < 768 * 256; i += stride) {
        int r = i >> 8, c = i & 255;
        float v;
        if (r < 256)      v = wq[r * 256 + c] * 0.0625f;      // fold d^-0.5 = 1/16
        else if (r < 512) v = wk[(r - 256) * 256 + c];
        else              v = wv[(r - 512) * 256 + c];
        wcat[i] = f2bf(v);
    }
    for (int i = i0; i < 256 * 256; i += stride) wmb[i] = f2bf(wm[i]);
}

// ---------------- K1: roll + LN + QKV projection (+ k L2-normalize) ----------------
__global__ __launch_bounds__(256)
void swa_ln_qkv(const float* __restrict__ x,
                const float* __restrict__ ln_g, const float* __restrict__ ln_b,
                const u16* __restrict__ wcat,
                const float* __restrict__ bq, const float* __restrict__ bk,
                const float* __restrict__ bv,
                u16* __restrict__ qbuf, u16* __restrict__ kbuf, u16* __restrict__ vbuf)
{
    __shared__ u16   xs[32][264];   // LN'd tile, bf16, padded stride
    __shared__ float stg[32][260];  // f32 staging for epilogue / k-norm
    __shared__ float bias[768];

    const int tid  = threadIdx.x;
    const int lane = tid & 63;
    const int wid  = tid >> 6;
    const int tok0 = blockIdx.x * 32;
    const int r16  = lane & 15;
    const int g4   = lane >> 4;

    for (int j = tid; j < 768; j += 256) {
        float b = (j < 256) ? bq[j] * 0.0625f : (j < 512 ? bk[j - 256] : bv[j - 512]);
        bias[j] = b;
    }
    f32x4 lg = *reinterpret_cast<const f32x4*>(ln_g + lane * 4);
    f32x4 lb = *reinterpret_cast<const f32x4*>(ln_b + lane * 4);

    // phase 1: each wave LNs 8 tokens (one wave per token-row)
    for (int it = 0; it < 8; ++it) {
        int tt  = wid * 8 + it;
        int tok = tok0 + tt;
        int b_  = tok / NPB;
        int rem = tok % NPB;
        int hs  = rem / 112, wsd = rem % 112;
        int h0  = hs - 3 + ((hs < 3) ? 112 : 0);   // shifted coords read x[(h-3)%112][(w-3)%112]
        int w0  = wsd - 3 + ((wsd < 3) ? 112 : 0);
        const float* row = x + (size_t)(b_ * NPB + h0 * 112 + w0) * CH;
        f32x4 v = *reinterpret_cast<const f32x4*>(row + lane * 4);
        float s  = v[0] + v[1] + v[2] + v[3];
        float sq = v[0]*v[0] + v[1]*v[1] + v[2]*v[2] + v[3]*v[3];
        #pragma unroll
        for (int m = 32; m; m >>= 1) { s += __shfl_xor(s, m); sq += __shfl_xor(sq, m); }
        float mu  = s * (1.0f / 256.0f);
        float var = sq * (1.0f / 256.0f) - mu * mu;
        float inv = 1.0f / sqrtf(var + 1e-5f);
        ushort4 o;
        o.x = f2bf((v[0] - mu) * inv * lg[0] + lb[0]);
        o.y = f2bf((v[1] - mu) * inv * lg[1] + lb[1]);
        o.z = f2bf((v[2] - mu) * inv * lg[2] + lb[2]);
        o.w = f2bf((v[3] - mu) * inv * lg[3] + lb[3]);
        *reinterpret_cast<ushort4*>(&xs[tt][lane * 4]) = o;
    }
    __syncthreads();

    // phase 2: 32x768 GEMM, wave owns 12 col-tiles x 2 row-tiles
    f32x4 zero4 = {0.f, 0.f, 0.f, 0.f};
    f32x4 acc[12][2];
    #pragma unroll
    for (int i = 0; i < 12; ++i) { acc[i][0] = zero4; acc[i][1] = zero4; }

    #pragma unroll
    for (int kk = 0; kk < 8; ++kk) {
        bfrag a0 = *reinterpret_cast<const bfrag*>(&xs[r16][kk * 32 + g4 * 8]);
        bfrag a1 = *reinterpret_cast<const bfrag*>(&xs[16 + r16][kk * 32 + g4 * 8]);
        #pragma unroll
        for (int ct = 0; ct < 12; ++ct) {
            const u16* wrow = wcat + (size_t)((wid * 12 + ct) * 16 + r16) * CH + kk * 32 + g4 * 8;
            bfrag bb = *reinterpret_cast<const bfrag*>(wrow);
            acc[ct][0] = __builtin_amdgcn_mfma_f32_16x16x32_bf16(a0, bb, acc[ct][0], 0, 0, 0);
            acc[ct][1] = __builtin_amdgcn_mfma_f32_16x16x32_bf16(a1, bb, acc[ct][1], 0, 0, 0);
        }
    }

    // epilogue: stage one 256-channel group at a time (q, k, v)
    auto stage_range = [&](int lo) {
        #pragma unroll
        for (int ct = 0; ct < 12; ++ct) {
            int ch = (wid * 12 + ct) * 16;
            if (ch >= lo && ch < lo + 256) {
                int c  = ch + r16;
                float bs = bias[c];
                int cl = c - lo;
                #pragma unroll
                for (int rt = 0; rt < 2; ++rt)
                    #pragma unroll
                    for (int r = 0; r < 4; ++r)
                        stg[rt * 16 + g4 * 4 + r][cl] = acc[ct][rt][r] + bs;
            }
        }
    };

    // ---- q ----
    stage_range(0);
    __syncthreads();
    for (int tt = wid; tt < 32; tt += 4) {
        f32x4 v = *reinterpret_cast<const f32x4*>(&stg[tt][lane * 4]);
        ushort4 o; o.x = f2bf(v[0]); o.y = f2bf(v[1]); o.z = f2bf(v[2]); o.w = f2bf(v[3]);
        *reinterpret_cast<ushort4*>(qbuf + (size_t)(tok0 + tt) * CH + lane * 4) = o;
    }
    __syncthreads();
    // ---- k (normalize rows) ----
    stage_range(256);
    __syncthreads();
    for (int tt = wid; tt < 32; tt += 4) {
        f32x4 v = *reinterpret_cast<const f32x4*>(&stg[tt][lane * 4]);
        float ss = v[0]*v[0] + v[1]*v[1] + v[2]*v[2] + v[3]*v[3];
        #pragma unroll
        for (int m = 32; m; m >>= 1) ss += __shfl_xor(ss, m);
        float inv = 1.0f / fmaxf(sqrtf(ss), 1e-12f);
        ushort4 o; o.x = f2bf(v[0]*inv); o.y = f2bf(v[1]*inv); o.z = f2bf(v[2]*inv); o.w = f2bf(v[3]*inv);
        *reinterpret_cast<ushort4*>(kbuf + (size_t)(tok0 + tt) * CH + lane * 4) = o;
    }
    __syncthreads();
    // ---- v ----
    stage_range(512);
    __syncthreads();
    for (int tt = wid; tt < 32; tt += 4) {
        f32x4 v = *reinterpret_cast<const f32x4*>(&stg[tt][lane * 4]);
        ushort4 o; o.x = f2bf(v[0]); o.y = f2bf(v[1]); o.z = f2bf(v[2]); o.w = f2bf(v[3]);
        *reinterpret_cast<ushort4*>(vbuf + (size_t)(tok0 + tt) * CH + lane * 4) = o;
    }
}

// ---------------- K2: local attention, one wave per 7-token window ----------------
// keys/values for window = 14 consecutive tokens starting at base-7
__global__ __launch_bounds__(256)
void swa_attn(const u16* qbuf, const u16* kbuf, const u16* vbuf, u16* obuf)
{
    __shared__ float plds[4][16][17];
    const int tid  = threadIdx.x;
    const int lane = tid & 63;
    const int wid  = tid >> 6;
    const int win  = blockIdx.x * 4 + wid;
    const int iw   = win % 1792;          // window index within batch
    const int base = win * 7;
    const int r16  = lane & 15;
    const int g4   = lane >> 4;

    int qrow = base + r16; if (qrow > NTOK - 1) qrow = NTOK - 1;   // rows >=7 are masked
    int krow = base - 7 + r16; if (krow < 0) krow = 0;             // first window prev masked
    const u16* qp = qbuf + (size_t)qrow * CH + g4 * 8;
    const u16* kp = kbuf + (size_t)krow * CH + g4 * 8;

    f32x4 s4 = {0.f, 0.f, 0.f, 0.f};
    #pragma unroll
    for (int kk = 0; kk < 8; ++kk) {
        bfrag a = *reinterpret_cast<const bfrag*>(qp + kk * 32);
        bfrag b = *reinterpret_cast<const bfrag*>(kp + kk * 32);
        s4 = __builtin_amdgcn_mfma_f32_16x16x32_bf16(a, b, s4, 0, 0, 0);
    }

    // D layout: col j = lane&15, row i = (lane>>4)*4 + reg
    const int  j     = r16;
    const bool first = (iw == 0);
    #pragma unroll
    for (int r = 0; r < 4; ++r) {
        int i = g4 * 4 + r;
        float s = s4[r];
        if (j == i + 7) s = -5.0e4f;                                   // self
        if (j > i + 7 || j >= 14 || (first && j < 7)) s = -3.0e38f;    // causal / pad
        s4[r] = s;
    }
    f32x4 mx = s4;
    #pragma unroll
    for (int off = 8; off; off >>= 1) {
        #pragma unroll
        for (int r = 0; r < 4; ++r) mx[r] = fmaxf(mx[r], __shfl_xor(mx[r], off));
    }
    f32x4 p;
    #pragma unroll
    for (int r = 0; r < 4; ++r) p[r] = __expf(s4[r] - mx[r]);
    f32x4 sm = p;
    #pragma unroll
    for (int off = 8; off; off >>= 1) {
        #pragma unroll
        for (int r = 0; r < 4; ++r) sm[r] += __shfl_xor(sm[r], off);
    }
    #pragma unroll
    for (int r = 0; r < 4; ++r) plds[wid][g4 * 4 + r][j] = p[r] / sm[r];
    __syncthreads();

    // PV on the VALU: lane owns 4 dims, 14 keys x 7 queries
    f32x4 zero4 = {0.f, 0.f, 0.f, 0.f};
    f32x4 oa[7];
    #pragma unroll
    for (int i = 0; i < 7; ++i) oa[i] = zero4;
    for (int jj = 0; jj < 14; ++jj) {
        int vrow = base - 7 + jj;
        if (vrow < 0) vrow = 0;        // masked (p=0) for first window
        ushort4 vr = *reinterpret_cast<const ushort4*>(vbuf + (size_t)vrow * CH + lane * 4);
        f32x4 vv; vv[0] = bf2f(vr.x); vv[1] = bf2f(vr.y); vv[2] = bf2f(vr.z); vv[3] = bf2f(vr.w);
        #pragma unroll
        for (int i = 0; i < 7; ++i) {
            float pp = plds[wid][i][jj];   // uniform address -> LDS broadcast
            oa[i][0] += pp * vv[0]; oa[i][1] += pp * vv[1];
            oa[i][2] += pp * vv[2]; oa[i][3] += pp * vv[3];
        }
    }
    #pragma unroll
    for (int i = 0; i < 7; ++i) {
        ushort4 o; o.x = f2bf(oa[i][0]); o.y = f2bf(oa[i][1]); o.z = f2bf(oa[i][2]); o.w = f2bf(oa[i][3]);
        *reinterpret_cast<ushort4*>(obuf + (size_t)(base + i) * CH + lane * 4) = o;
    }
}

// ---------------- K3: unshift + residual + LN + MLP(GELU) + add ----------------
__global__ __launch_bounds__(256)
void swa_mlp(const float* __restrict__ x, const u16* __restrict__ abuf,
             const float* __restrict__ ln_g, const float* __restrict__ ln_b,
             const u16* __restrict__ wmb, const float* __restrict__ mbias,
             float* __restrict__ out)
{
    __shared__ u16   xs[32][264];
    __shared__ float rsd[32][260];
    __shared__ float bias[256];
    const int tid  = threadIdx.x;
    const int lane = tid & 63;
    const int wid  = tid >> 6;
    const int tok0 = blockIdx.x * 32;
    const int r16  = lane & 15;
    const int g4   = lane >> 4;

    if (tid < 256) bias[tid] = mbias[tid];
    f32x4 lg = *reinterpret_cast<const f32x4*>(ln_g + lane * 4);
    f32x4 lb = *reinterpret_cast<const f32x4*>(ln_b + lane * 4);

    for (int it = 0; it < 8; ++it) {
        int tt  = wid * 8 + it;
        int tok = tok0 + tt;
        int b_  = tok / NPB, rem = tok % NPB;
        int h = rem / 112, w = rem % 112;
        int hs = h + 3;  if (hs >= 112) hs -= 112;   // residual[h][w] = attn[(h+3)%112][(w+3)%112] + x[h][w]
        int ws_ = w + 3; if (ws_ >= 112) ws_ -= 112;
        const u16* arow = abuf + (size_t)(b_ * NPB + hs * 112 + ws_) * CH;
        ushort4 av = *reinterpret_cast<const ushort4*>(arow + lane * 4);
        f32x4 xv = *reinterpret_cast<const f32x4*>(x + (size_t)tok * CH + lane * 4);
        f32x4 rv;
        rv[0] = xv[0] + bf2f(av.x); rv[1] = xv[1] + bf2f(av.y);
        rv[2] = xv[2] + bf2f(av.z); rv[3] = xv[3] + bf2f(av.w);
        *reinterpret_cast<f32x4*>(&rsd[tt][lane * 4]) = rv;
        float s  = rv[0] + rv[1] + rv[2] + rv[3];
        float sq = rv[0]*rv[0] + rv[1]*rv[1] + rv[2]*rv[2] + rv[3]*rv[3];
        #pragma unroll
        for (int m = 32; m; m >>= 1) { s += __shfl_xor(s, m); sq += __shfl_xor(sq, m); }
        float mu  = s * (1.0f / 256.0f);
        float var = sq * (1.0f / 256.0f) - mu * mu;
        float inv = 1.0f / sqrtf(var + 1e-5f);
        ushort4 o;
        o.x = f2bf((rv[0] - mu) * inv * lg[0] + lb[0]);
        o.y = f2bf((rv[1] - mu) * inv * lg[1] + lb[1]);
        o.z = f2bf((rv[2] - mu) * inv * lg[2] + lb[2]);
        o.w = f2bf((rv[3] - mu) * inv * lg[3] + lb[3]);
        *reinterpret_cast<ushort4*>(&xs[tt][lane * 4]) = o;
    }
    __syncthreads();

    f32x4 zero4 = {0.f, 0.f, 0.f, 0.f};
    f32x4 acc[4][2];
    #pragma unroll
    for (int i = 0; i < 4; ++i) { acc[i][0] = zero4; acc[i][1] = zero4; }

    #pragma unroll
    for (int kk = 0; kk < 8; ++kk) {
        bfrag a0 = *reinterpret_cast<const bfrag*>(&xs[r16][kk * 32 + g4 * 8]);
        bfrag a1 = *reinterpret_cast<const bfrag*>(&xs[16 + r16][kk * 32 + g4 * 8]);
        #pragma unroll
        for (int ct = 0; ct < 4; ++ct) {
            const u16* wrow = wmb + (size_t)((wid * 4 + ct) * 16 + r16) * CH + kk * 32 + g4 * 8;
            bfrag bb = *reinterpret_cast<const bfrag*>(wrow);
            acc[ct][0] = __builtin_amdgcn_mfma_f32_16x16x32_bf16(a0, bb, acc[ct][0], 0, 0, 0);
            acc[ct][1] = __builtin_amdgcn_mfma_f32_16x16x32_bf16(a1, bb, acc[ct][1], 0, 0, 0);
        }
    }

    #pragma unroll
    for (int ct = 0; ct < 4; ++ct) {
        int ch = (wid * 4 + ct) * 16 + r16;
        float bs = bias[ch];
        #pragma unroll
        for (int rt = 0; rt < 2; ++rt)
            #pragma unroll
            for (int r = 0; r < 4; ++r) {
                int tr = rt * 16 + g4 * 4 + r;
                float val = acc[ct][rt][r] + bs;
                float ge  = 0.5f * val * (1.0f + erff(val * 0.70710678118654752f));   // exact gelu
                out[(size_t)(tok0 + tr) * CH + ch] = ge + rsd[tr][ch];
            }
    }
}

extern "C" void kernel_launch(void* const* d_in, const int* in_sizes, int n_in,
                              void* d_out, int out_size, void* d_ws, size_t ws_size,
                              hipStream_t stream)
{
    const float* x     = (const float*)d_in[0];
    const float* ln_g  = (const float*)d_in[1];
    const float* ln_b  = (const float*)d_in[2];
    const float* wq_w  = (const float*)d_in[3];
    const float* wq_b  = (const float*)d_in[4];
    const float* wk_w  = (const float*)d_in[5];
    const float* wk_b  = (const float*)d_in[6];
    const float* wv_w  = (const float*)d_in[7];
    const float* wv_b  = (const float*)d_in[8];
    const float* mlp_w = (const float*)d_in[9];
    const float* mlp_b = (const float*)d_in[10];

    char* ws = (char*)d_ws;
    u16* wcat = (u16*)ws;                       // 768*256 bf16          (393216 B)
    u16* wmb  = (u16*)(ws + 393216);            // 256*256 bf16          (131072 B)
    u16* qbuf = (u16*)(ws + 524288);            // NTOK*256 bf16; attention output overwrites it
    // k,v (bf16) exactly fill d_out (2 * 51380224 = 102760448 B); K3 rewrites d_out afterwards
    u16* kbuf = (u16*)d_out;
    u16* vbuf = (u16*)d_out + (size_t)NTOK * CH;

    swa_prep  <<<256,  256, 0, stream>>>(wq_w, wk_w, wv_w, mlp_w, wcat, wmb);
    swa_ln_qkv<<<3136, 256, 0, stream>>>(x, ln_g, ln_b, wcat, wq_b, wk_b, wv_b, qbuf, kbuf, vbuf);
    swa_attn  <<<3584, 256, 0, stream>>>(qbuf, kbuf, vbuf, qbuf);
    swa_mlp   <<<3136, 256, 0, stream>>>(x, qbuf, ln_g, ln_b, wmb, mlp_b, (float*)d_out);
}

// Round 2
// 401.200 us; speedup vs baseline: 1.0683x; 1.0683x over previous
//
#include <hip/hip_runtime.h>

#define NTOK 100352   // 8*112*112
#define NPB  12544    // tokens per batch (112*112)
#define CH   256

typedef unsigned short u16;
typedef float f32x4 __attribute__((ext_vector_type(4)));
typedef short bfrag __attribute__((ext_vector_type(8)));   // 8 bf16 = 4 VGPRs

static __device__ __forceinline__ u16 f2bf(float f) {
    union { float f; unsigned u; } v; v.f = f;
    unsigned r = v.u + 0x7FFFu + ((v.u >> 16) & 1u);   // RNE
    return (u16)(r >> 16);
}
static __device__ __forceinline__ float bf2f(u16 h) {
    union { unsigned u; float f; } v; v.u = ((unsigned)h) << 16;
    return v.f;
}

// ---------------- K0: weight prep (fp32 -> bf16, fold q scale) ----------------
__global__ __launch_bounds__(256)
void swa_prep(const float* __restrict__ wq, const float* __restrict__ wk,
              const float* __restrict__ wv, const float* __restrict__ wm,
              u16* __restrict__ wcat, u16* __restrict__ wmb)
{
    int i0 = blockIdx.x * 256 + threadIdx.x;
    int stride = gridDim.x * 256;
    for (int i = i0; i < 768 * 256; i += stride) {
        int r = i >> 8, c = i & 255;
        float v;
        if (r < 256)      v = wq[r * 256 + c] * 0.0625f;      // fold d^-0.5 = 1/16
        else if (r < 512) v = wk[(r - 256) * 256 + c];
        else              v = wv[(r - 512) * 256 + c];
        wcat[i] = f2bf(v);
    }
    for (int i = i0; i < 256 * 256; i += stride) wmb[i] = f2bf(wm[i]);
}

// ---------------- K1: roll + LN + QKV projection, weights-stationary ----------------
// grid: 392 strips x 3 sections (q,k,v). block = 256 thr / 4 waves.
// wave owns 64 output channels; their weights (64x256 bf16) live in VGPRs.
// per iter: 32 tokens staged LN'd-bf16 into swizzled LDS, 64 MFMA/wave.
__global__ __launch_bounds__(256, 2)
void swa_qkv2(const float* __restrict__ x,
              const float* __restrict__ ln_g, const float* __restrict__ ln_b,
              const u16* __restrict__ wcat,
              const float* __restrict__ bq, const float* __restrict__ bk,
              const float* __restrict__ bv,
              u16* __restrict__ qbuf, u16* __restrict__ kbuf, u16* __restrict__ vbuf)
{
    __shared__ u16  xs[32 * 256];                    // 16 KB, chunk-XOR swizzled
    __shared__ float lng[256], lnb[256];
    __shared__ float __attribute__((aligned(16))) knorm[32][4];

    const int tid  = threadIdx.x;
    const int lane = tid & 63;
    const int wid  = tid >> 6;
    const int r16  = lane & 15;
    const int g4   = lane >> 4;

    // XCD-bijective swizzle: 1176 = 8 * 147; 147 = 49 strips * 3 secs per XCD chunk
    const int swz   = (blockIdx.x & 7) * 147 + (blockIdx.x >> 3);
    const int sec   = swz % 3;                       // 0=q 1=k 2=v
    const int strip = swz / 3;
    const int tok0  = strip * 256;                   // 8 iters x 32 tokens

    if (tid < 256) { lng[tid] = ln_g[tid]; lnb[tid] = ln_b[tid]; }

    // ---- weight prologue: 4 ct-tiles x 8 kk bfrags, held in VGPRs ----
    const float* bsec = (sec == 0) ? bq : (sec == 1) ? bk : bv;
    u16*         outp = (sec == 0) ? qbuf : (sec == 1) ? kbuf : vbuf;
    const float  bscale = (sec == 0) ? 0.0625f : 1.0f;
    bfrag wv_[4][8];
    float bias[4];
    #pragma unroll
    for (int ct = 0; ct < 4; ++ct) {
        int chl = wid * 64 + ct * 16 + r16;          // channel within section
        const u16* wrow = wcat + (size_t)(sec * 256 + chl) * CH + g4 * 8;
        #pragma unroll
        for (int kk = 0; kk < 8; ++kk)
            wv_[ct][kk] = *reinterpret_cast<const bfrag*>(wrow + kk * 32);
        bias[ct] = bsec[chl] * bscale;
    }

    // ---- x-staging mapping: 8 threads per token row ----
    const int r   = tid >> 3;                        // token row within 32-tile
    const int sub = tid & 7;
    f32x4 xv[8];

    auto load_x = [&](int it) {
        int tok = tok0 + it * 32 + r;
        int b_  = tok / NPB;
        int rem = tok - b_ * NPB;
        int hs  = rem / 112, wsd = rem - hs * 112;
        int h0  = hs - 3 + ((hs < 3) ? 112 : 0);     // shifted read
        int w0  = wsd - 3 + ((wsd < 3) ? 112 : 0);
        const float* rowp = x + (size_t)(b_ * NPB + h0 * 112 + w0) * CH;
        #pragma unroll
        for (int j = 0; j < 8; ++j)
            xv[j] = *reinterpret_cast<const f32x4*>(rowp + (sub + 8 * j) * 4);
    };

    load_x(0);
    __syncthreads();   // lng/lnb ready

    char* xsb = (char*)xs;

    for (int it = 0; it < 8; ++it) {
        // ---- LN + swizzled bf16 stage ----
        float s = 0.f, sq = 0.f;
        #pragma unroll
        for (int j = 0; j < 8; ++j) {
            s  += xv[j][0] + xv[j][1] + xv[j][2] + xv[j][3];
            sq += xv[j][0]*xv[j][0] + xv[j][1]*xv[j][1] + xv[j][2]*xv[j][2] + xv[j][3]*xv[j][3];
        }
        s  += __shfl_xor(s, 1);  sq += __shfl_xor(sq, 1);
        s  += __shfl_xor(s, 2);  sq += __shfl_xor(sq, 2);
        s  += __shfl_xor(s, 4);  sq += __shfl_xor(sq, 4);
        float mu  = s * (1.0f / 256.0f);
        float var = sq * (1.0f / 256.0f) - mu * mu;
        float inv = 1.0f / sqrtf(var + 1e-5f);
        #pragma unroll
        for (int j = 0; j < 8; ++j) {
            int cf = sub + 8 * j;                    // f32x4 chunk index (0..63)
            f32x4 g = *reinterpret_cast<const f32x4*>(&lng[cf * 4]);
            f32x4 b = *reinterpret_cast<const f32x4*>(&lnb[cf * 4]);
            unsigned lo = f2bf((xv[j][0] - mu) * inv * g[0] + b[0])
                        | ((unsigned)f2bf((xv[j][1] - mu) * inv * g[1] + b[1]) << 16);
            unsigned hi = f2bf((xv[j][2] - mu) * inv * g[2] + b[2])
                        | ((unsigned)f2bf((xv[j][3] - mu) * inv * g[3] + b[3]) << 16);
            int c = cf >> 1, h = cf & 1;             // 16B chunk + half
            int off = r * 512 + ((c ^ (r & 7)) << 4) + h * 8;
            uint2 p; p.x = lo; p.y = hi;
            *reinterpret_cast<uint2*>(xsb + off) = p;
        }
        __syncthreads();

        if (it < 7) load_x(it + 1);                  // overlap HBM latency with MFMA

        // ---- GEMM: A from swizzled LDS, B stationary in regs ----
        f32x4 acc[4][2];
        #pragma unroll
        for (int ct = 0; ct < 4; ++ct) { acc[ct][0] = (f32x4)0.f; acc[ct][1] = (f32x4)0.f; }
        #pragma unroll
        for (int kk = 0; kk < 8; ++kk) {
            int csw = ((kk * 4 + g4) ^ (r16 & 7)) << 4;
            bfrag a0 = *reinterpret_cast<const bfrag*>(xsb + r16 * 512 + csw);
            bfrag a1 = *reinterpret_cast<const bfrag*>(xsb + (16 + r16) * 512 + csw);
            #pragma unroll
            for (int ct = 0; ct < 4; ++ct) {
                acc[ct][0] = __builtin_amdgcn_mfma_f32_16x16x32_bf16(a0, wv_[ct][kk], acc[ct][0], 0, 0, 0);
                acc[ct][1] = __builtin_amdgcn_mfma_f32_16x16x32_bf16(a1, wv_[ct][kk], acc[ct][1], 0, 0, 0);
            }
        }

        // ---- epilogue ----
        float invn[2][4];
        if (sec == 1) {                              // k: L2-normalize rows (fp32, post-bias)
            float part[2][4];
            #pragma unroll
            for (int rt = 0; rt < 2; ++rt)
                #pragma unroll
                for (int rr = 0; rr < 4; ++rr) {
                    float p = 0.f;
                    #pragma unroll
                    for (int ct = 0; ct < 4; ++ct) {
                        float vv = acc[ct][rt][rr] + bias[ct];
                        p += vv * vv;
                    }
                    p += __shfl_xor(p, 1); p += __shfl_xor(p, 2);
                    p += __shfl_xor(p, 4); p += __shfl_xor(p, 8);
                    part[rt][rr] = p;                // wave-partial (64 chs) per token
                }
            if (r16 == 0) {
                #pragma unroll
                for (int rt = 0; rt < 2; ++rt)
                    #pragma unroll
                    for (int rr = 0; rr < 4; ++rr)
                        knorm[rt * 16 + g4 * 4 + rr][wid] = part[rt][rr];
            }
            __syncthreads();
            #pragma unroll
            for (int rt = 0; rt < 2; ++rt)
                #pragma unroll
                for (int rr = 0; rr < 4; ++rr) {
                    f32x4 k4 = *reinterpret_cast<const f32x4*>(knorm[rt * 16 + g4 * 4 + rr]);
                    float sum = k4[0] + k4[1] + k4[2] + k4[3];
                    invn[rt][rr] = 1.0f / fmaxf(sqrtf(sum), 1e-12f);
                }
        }
        #pragma unroll
        for (int ct = 0; ct < 4; ++ct) {
            int ch = wid * 64 + ct * 16 + r16;
            #pragma unroll
            for (int rt = 0; rt < 2; ++rt)
                #pragma unroll
                for (int rr = 0; rr < 4; ++rr) {
                    float vv = acc[ct][rt][rr] + bias[ct];
                    if (sec == 1) vv *= invn[rt][rr];
                    int tok = tok0 + it * 32 + rt * 16 + g4 * 4 + rr;
                    outp[(size_t)tok * CH + ch] = f2bf(vv);
                }
        }
        __syncthreads();                             // protect xs before next stage
    }
}

// ---------------- K2: local attention, one wave per 7-token window ----------------
__global__ __launch_bounds__(256)
void swa_attn(const u16* qbuf, const u16* kbuf, const u16* vbuf, u16* obuf)
{
    __shared__ float plds[4][16][17];
    const int tid  = threadIdx.x;
    const int lane = tid & 63;
    const int wid  = tid >> 6;
    const int win  = blockIdx.x * 4 + wid;
    const int iw   = win % 1792;          // window index within batch
    const int base = win * 7;
    const int r16  = lane & 15;
    const int g4   = lane >> 4;

    int qrow = base + r16; if (qrow > NTOK - 1) qrow = NTOK - 1;   // rows >=7 are masked
    int krow = base - 7 + r16; if (krow < 0) krow = 0;             // first window prev masked
    const u16* qp = qbuf + (size_t)qrow * CH + g4 * 8;
    const u16* kp = kbuf + (size_t)krow * CH + g4 * 8;

    f32x4 s4 = {0.f, 0.f, 0.f, 0.f};
    #pragma unroll
    for (int kk = 0; kk < 8; ++kk) {
        bfrag a = *reinterpret_cast<const bfrag*>(qp + kk * 32);
        bfrag b = *reinterpret_cast<const bfrag*>(kp + kk * 32);
        s4 = __builtin_amdgcn_mfma_f32_16x16x32_bf16(a, b, s4, 0, 0, 0);
    }

    const int  j     = r16;
    const bool first = (iw == 0);
    #pragma unroll
    for (int rr = 0; rr < 4; ++rr) {
        int i = g4 * 4 + rr;
        float s = s4[rr];
        if (j == i + 7) s = -5.0e4f;                                   // self
        if (j > i + 7 || j >= 14 || (first && j < 7)) s = -3.0e38f;    // causal / pad
        s4[rr] = s;
    }
    f32x4 mx = s4;
    #pragma unroll
    for (int off = 8; off; off >>= 1) {
        #pragma unroll
        for (int rr = 0; rr < 4; ++rr) mx[rr] = fmaxf(mx[rr], __shfl_xor(mx[rr], off));
    }
    f32x4 p;
    #pragma unroll
    for (int rr = 0; rr < 4; ++rr) p[rr] = __expf(s4[rr] - mx[rr]);
    f32x4 sm = p;
    #pragma unroll
    for (int off = 8; off; off >>= 1) {
        #pragma unroll
        for (int rr = 0; rr < 4; ++rr) sm[rr] += __shfl_xor(sm[rr], off);
    }
    #pragma unroll
    for (int rr = 0; rr < 4; ++rr) plds[wid][g4 * 4 + rr][j] = p[rr] / sm[rr];
    __syncthreads();

    f32x4 zero4 = {0.f, 0.f, 0.f, 0.f};
    f32x4 oa[7];
    #pragma unroll
    for (int i = 0; i < 7; ++i) oa[i] = zero4;
    for (int jj = 0; jj < 14; ++jj) {
        int vrow = base - 7 + jj;
        if (vrow < 0) vrow = 0;        // masked (p=0) for first window
        ushort4 vr = *reinterpret_cast<const ushort4*>(vbuf + (size_t)vrow * CH + lane * 4);
        f32x4 vvv; vvv[0] = bf2f(vr.x); vvv[1] = bf2f(vr.y); vvv[2] = bf2f(vr.z); vvv[3] = bf2f(vr.w);
        #pragma unroll
        for (int i = 0; i < 7; ++i) {
            float pp = plds[wid][i][jj];
            oa[i][0] += pp * vvv[0]; oa[i][1] += pp * vvv[1];
            oa[i][2] += pp * vvv[2]; oa[i][3] += pp * vvv[3];
        }
    }
    #pragma unroll
    for (int i = 0; i < 7; ++i) {
        ushort4 o; o.x = f2bf(oa[i][0]); o.y = f2bf(oa[i][1]); o.z = f2bf(oa[i][2]); o.w = f2bf(oa[i][3]);
        *reinterpret_cast<ushort4*>(obuf + (size_t)(base + i) * CH + lane * 4) = o;
    }
}

// ---------------- K3: unshift + residual + LN + MLP(GELU) + add ----------------
__global__ __launch_bounds__(256)
void swa_mlp(const float* __restrict__ x, const u16* __restrict__ abuf,
             const float* __restrict__ ln_g, const float* __restrict__ ln_b,
             const u16* __restrict__ wmb, const float* __restrict__ mbias,
             float* __restrict__ out)
{
    __shared__ u16   xs[32][264];
    __shared__ float rsd[32][260];
    __shared__ float bias[256];
    const int tid  = threadIdx.x;
    const int lane = tid & 63;
    const int wid  = tid >> 6;
    const int tok0 = blockIdx.x * 32;
    const int r16  = lane & 15;
    const int g4   = lane >> 4;

    if (tid < 256) bias[tid] = mbias[tid];
    f32x4 lg = *reinterpret_cast<const f32x4*>(ln_g + lane * 4);
    f32x4 lb = *reinterpret_cast<const f32x4*>(ln_b + lane * 4);

    for (int it = 0; it < 8; ++it) {
        int tt  = wid * 8 + it;
        int tok = tok0 + tt;
        int b_  = tok / NPB, rem = tok % NPB;
        int h = rem / 112, w = rem % 112;
        int hs = h + 3;  if (hs >= 112) hs -= 112;
        int ws_ = w + 3; if (ws_ >= 112) ws_ -= 112;
        const u16* arow = abuf + (size_t)(b_ * NPB + hs * 112 + ws_) * CH;
        ushort4 av = *reinterpret_cast<const ushort4*>(arow + lane * 4);
        f32x4 xv = *reinterpret_cast<const f32x4*>(x + (size_t)tok * CH + lane * 4);
        f32x4 rv;
        rv[0] = xv[0] + bf2f(av.x); rv[1] = xv[1] + bf2f(av.y);
        rv[2] = xv[2] + bf2f(av.z); rv[3] = xv[3] + bf2f(av.w);
        *reinterpret_cast<f32x4*>(&rsd[tt][lane * 4]) = rv;
        float s  = rv[0] + rv[1] + rv[2] + rv[3];
        float sq = rv[0]*rv[0] + rv[1]*rv[1] + rv[2]*rv[2] + rv[3]*rv[3];
        #pragma unroll
        for (int m = 32; m; m >>= 1) { s += __shfl_xor(s, m); sq += __shfl_xor(sq, m); }
        float mu  = s * (1.0f / 256.0f);
        float var = sq * (1.0f / 256.0f) - mu * mu;
        float inv = 1.0f / sqrtf(var + 1e-5f);
        ushort4 o;
        o.x = f2bf((rv[0] - mu) * inv * lg[0] + lb[0]);
        o.y = f2bf((rv[1] - mu) * inv * lg[1] + lb[1]);
        o.z = f2bf((rv[2] - mu) * inv * lg[2] + lb[2]);
        o.w = f2bf((rv[3] - mu) * inv * lg[3] + lb[3]);
        *reinterpret_cast<ushort4*>(&xs[tt][lane * 4]) = o;
    }
    __syncthreads();

    f32x4 zero4 = {0.f, 0.f, 0.f, 0.f};
    f32x4 acc[4][2];
    #pragma unroll
    for (int i = 0; i < 4; ++i) { acc[i][0] = zero4; acc[i][1] = zero4; }

    #pragma unroll
    for (int kk = 0; kk < 8; ++kk) {
        bfrag a0 = *reinterpret_cast<const bfrag*>(&xs[r16][kk * 32 + g4 * 8]);
        bfrag a1 = *reinterpret_cast<const bfrag*>(&xs[16 + r16][kk * 32 + g4 * 8]);
        #pragma unroll
        for (int ct = 0; ct < 4; ++ct) {
            const u16* wrow = wmb + (size_t)((wid * 4 + ct) * 16 + r16) * CH + kk * 32 + g4 * 8;
            bfrag bb = *reinterpret_cast<const bfrag*>(wrow);
            acc[ct][0] = __builtin_amdgcn_mfma_f32_16x16x32_bf16(a0, bb, acc[ct][0], 0, 0, 0);
            acc[ct][1] = __builtin_amdgcn_mfma_f32_16x16x32_bf16(a1, bb, acc[ct][1], 0, 0, 0);
        }
    }

    #pragma unroll
    for (int ct = 0; ct < 4; ++ct) {
        int ch = (wid * 4 + ct) * 16 + r16;
        float bs = bias[ch];
        #pragma unroll
        for (int rt = 0; rt < 2; ++rt)
            #pragma unroll
            for (int rr = 0; rr < 4; ++rr) {
                int tr = rt * 16 + g4 * 4 + rr;
                float val = acc[ct][rt][rr] + bs;
                float ge  = 0.5f * val * (1.0f + erff(val * 0.70710678118654752f));
                out[(size_t)(tok0 + tr) * CH + ch] = ge + rsd[tr][ch];
            }
    }
}

extern "C" void kernel_launch(void* const* d_in, const int* in_sizes, int n_in,
                              void* d_out, int out_size, void* d_ws, size_t ws_size,
                              hipStream_t stream)
{
    const float* x     = (const float*)d_in[0];
    const float* ln_g  = (const float*)d_in[1];
    const float* ln_b  = (const float*)d_in[2];
    const float* wq_w  = (const float*)d_in[3];
    const float* wq_b  = (const float*)d_in[4];
    const float* wk_w  = (const float*)d_in[5];
    const float* wk_b  = (const float*)d_in[6];
    const float* wv_w  = (const float*)d_in[7];
    const float* wv_b  = (const float*)d_in[8];
    const float* mlp_w = (const float*)d_in[9];
    const float* mlp_b = (const float*)d_in[10];

    char* ws = (char*)d_ws;
    u16* wcat = (u16*)ws;                       // 768*256 bf16
    u16* wmb  = (u16*)(ws + 393216);            // 256*256 bf16
    u16* qbuf = (u16*)(ws + 524288);            // q, later attn output
    u16* kbuf = (u16*)d_out;                    // k,v fill d_out; K3 rewrites it
    u16* vbuf = (u16*)d_out + (size_t)NTOK * CH;

    swa_prep <<<256,  256, 0, stream>>>(wq_w, wk_w, wv_w, mlp_w, wcat, wmb);
    swa_qkv2 <<<1176, 256, 0, stream>>>(x, ln_g, ln_b, wcat, wq_b, wk_b, wv_b, qbuf, kbuf, vbuf);
    swa_attn <<<3584, 256, 0, stream>>>(qbuf, kbuf, vbuf, qbuf);
    swa_mlp  <<<3136, 256, 0, stream>>>(x, qbuf, ln_g, ln_b, wmb, mlp_b, (float*)d_out);
}